// Round 8
// baseline (267.936 us; speedup 1.0000x reference)
//
#include <hip/hip_runtime.h>
#include <cstdint>
#include <cstddef>

#define BQ 16
#define NT 1024
#define CH 768
#define HIDN 128
#define OUTF 2304
#define MTOT (BQ*NT)   // 16384 tokens

typedef __attribute__((ext_vector_type(4))) float f32x4;
typedef __attribute__((ext_vector_type(8))) short short8;   // 8 x bf16 payload

// ---------- small helpers ----------
__device__ __forceinline__ unsigned short f2bf(float f){
  unsigned u = __float_as_uint(f);
  u += 0x7FFFu + ((u >> 16) & 1u);      // RNE
  return (unsigned short)(u >> 16);
}
__device__ __forceinline__ float bf2f(unsigned short h){
  return __uint_as_float(((unsigned)h) << 16);
}

__device__ __forceinline__ void gload16(const void* g, void* l){
  __builtin_amdgcn_global_load_lds((const __attribute__((address_space(1))) void*)g,
                                   (__attribute__((address_space(3))) void*)l, 16, 0, 0);
}

__device__ __forceinline__ void mfma16(f32x4& d, short8 a, short8 b){
  asm volatile("v_mfma_f32_16x16x32_bf16 %0, %1, %2, %0" : "+v"(d) : "v"(a), "v"(b));
}

// ---------- fused fp32 -> bf16 convert of all 5 tensors (grid-stride) ----------
__global__ void k_f2bf_all(const float* __restrict__ in0, const float* __restrict__ in1,
                           const float* __restrict__ in2, const float* __restrict__ in3,
                           const float* __restrict__ in4,
                           unsigned short* __restrict__ o0, unsigned short* __restrict__ o1,
                           unsigned short* __restrict__ o2, unsigned short* __restrict__ o3,
                           unsigned short* __restrict__ o4)
{
  const long step = (long)2048 * 256 * 4;
  for (long i = (long)(blockIdx.x * 256 + threadIdx.x) * 4; i < 27131904L; i += step){
    const float* s; unsigned short* d; long off;
    if      (i < 12582912L){ s = in0; d = o0; off = i; }
    else if (i < 25165824L){ s = in1; d = o1; off = i - 12582912L; }
    else if (i < 26935296L){ s = in2; d = o2; off = i - 25165824L; }
    else if (i < 27033600L){ s = in3; d = o3; off = i - 26935296L; }
    else                   { s = in4; d = o4; off = i - 27033600L; }
    float4 v = *reinterpret_cast<const float4*>(s + off);
    ushort4 o;
    o.x = f2bf(v.x); o.y = f2bf(v.y); o.z = f2bf(v.z); o.w = f2bf(v.w);
    *reinterpret_cast<ushort4*>(d + off) = o;
  }
}

// ---------- prep: qb2 = qkv_b + qkv_w@fc2_b; w2tb = fc2_w^T (bf16); z128 ----------
__global__ void k_prep(const float* __restrict__ qkv_w, const float* __restrict__ qkv_b,
                       const float* __restrict__ fc2_w, const float* __restrict__ fc2_b,
                       float* __restrict__ qb2, unsigned short* __restrict__ w2tb,
                       float* __restrict__ z128)
{
  const int bid = blockIdx.x, tid = threadIdx.x;
  if (bid < 9){
    __shared__ float fb[CH];
    for (int i = tid; i < CH; i += 256) fb[i] = fc2_b[i];
    __syncthreads();
    int o = bid*256 + tid;
    float s = qkv_b[o];
    const float* wr = qkv_w + (size_t)o * CH;
    for (int c = 0; c < CH; ++c) s += wr[c] * fb[c];
    qb2[o] = s;
  } else if (bid < 25){
    int base = (bid - 9) * 6144;
    #pragma unroll 4
    for (int i = 0; i < 24; ++i){
      int e = base + i*256 + tid;           // e < 98304
      int c = e >> 7, h = e & 127;
      w2tb[(size_t)h * CH + c] = f2bf(fc2_w[e]);
    }
  } else {
    if (tid < 128) z128[tid] = 0.f;
  }
}

// ============================================================================
// 256x256 8-phase GEMM body — dual-K-source: tiles [0,TS) from A0/B0 (stride
// K0), tiles [TS,T) from A1/B1 (stride K1). q1: <12,12> single-source.
// q2: <14,12> concat [x2b|G] x [wqb|W2q].
// ============================================================================
#define STAGE(matB_, buf_, h_, t_) { \
    const unsigned short* g_; size_t rk_; \
    if ((t_) < TS){ g_ = ((matB_) ? Bbase0 : Abase0) + (size_t)(h_)*128*K0 + (size_t)(t_)*64; rk_ = (size_t)64*K0; } \
    else          { g_ = ((matB_) ? Bbase1 : Abase1) + (size_t)(h_)*128*K1 + (size_t)((t_)-TS)*64; rk_ = (size_t)64*K1; } \
    char* d_ = ldsWaveDst + (matB_)*65536 + (buf_)*32768 + (h_)*16384; \
    gload16(g_, d_); \
    gload16(g_ + rk_, d_ + 8192); \
  }

#define PH_OPEN() \
    asm volatile("s_barrier" ::: "memory"); \
    asm volatile("s_waitcnt lgkmcnt(0)" ::: "memory"); \
    __builtin_amdgcn_sched_barrier(0); \
    __builtin_amdgcn_s_setprio(1);

#define PH_CLOSE() \
    __builtin_amdgcn_s_setprio(0); \
    asm volatile("s_barrier" ::: "memory");

#define MF16(mb, nb, BV) \
    _Pragma("unroll") \
    for (int ks = 0; ks < 2; ++ks) \
      _Pragma("unroll") \
      for (int mf = 0; mf < 4; ++mf) \
        _Pragma("unroll") \
        for (int nf = 0; nf < 2; ++nf) \
          mfma16(acc[(mb)+mf][(nb)+nf], av[mf][ks], BV[nf][ks]);

#define TILE(t_, b_) { \
    const int t = (t_); const int b = (b_); \
    _Pragma("unroll") for (int mf = 0; mf < 4; ++mf){ av[mf][0]=ldA(b,mf,0); av[mf][1]=ldA(b,mf,1); } \
    _Pragma("unroll") for (int nf = 0; nf < 2; ++nf){ b0v[nf][0]=ldB(b,nf,0); b0v[nf][1]=ldB(b,nf,1); } \
    if (t+1 < T) STAGE(0, b^1, 1, t+1); \
    PH_OPEN(); MF16(0,0,b0v); PH_CLOSE(); \
    _Pragma("unroll") for (int nf = 0; nf < 2; ++nf){ b1v[nf][0]=ldB(b,2+nf,0); b1v[nf][1]=ldB(b,2+nf,1); } \
    if (t+1 < T) STAGE(1, b^1, 0, t+1); \
    PH_OPEN(); MF16(0,2,b1v); PH_CLOSE(); \
    _Pragma("unroll") for (int mf = 0; mf < 4; ++mf){ av[mf][0]=ldA(b,4+mf,0); av[mf][1]=ldA(b,4+mf,1); } \
    if (t+2 < T) STAGE(0, b, 0, t+2); \
    PH_OPEN(); MF16(4,2,b1v); PH_CLOSE(); \
    if (t+2 < T) STAGE(1, b, 1, t+2); \
    PH_OPEN(); MF16(4,0,b0v); \
    __builtin_amdgcn_s_setprio(0); \
    if (t+2 < T) { asm volatile("s_waitcnt vmcnt(4)" ::: "memory"); } \
    else         { asm volatile("s_waitcnt vmcnt(0)" ::: "memory"); } \
    asm volatile("s_barrier" ::: "memory"); \
  }

template<int T, int TS>   // T even; tiles >= TS read the K1-stride source
__device__ __forceinline__
void gemm256_body(char* lds8,
                  const unsigned short* __restrict__ A0, const unsigned short* __restrict__ A1,
                  const unsigned short* __restrict__ B0, const unsigned short* __restrict__ B1,
                  const float* __restrict__ bias,
                  float* __restrict__ C,
                  int N, int K0, int K1, int nbn, int bid, int nwg)
{
  const int tid = threadIdx.x;
  const int ln = tid & 63, wv = tid >> 6;
  const int wm = wv >> 2, wn = wv & 3;
  const int llo = ln & 15, lhi = ln >> 4;

  const int cpx = nwg >> 3;
  const int swz = (bid & 7) * cpx + (bid >> 3);
  const int bm = swz / nbn, bn = swz % nbn;
  const int m0 = bm * 256, n0 = bn * 256;

  const int srow = tid >> 3;
  const int sslot = (tid & 7) ^ (srow & 7);
  const unsigned short* Abase0 = A0 + (size_t)(m0 + srow) * K0 + sslot * 8;
  const unsigned short* Abase1 = A1 + (size_t)(m0 + srow) * K1 + sslot * 8;
  const unsigned short* Bbase0 = B0 + (size_t)(n0 + srow) * K0 + sslot * 8;
  const unsigned short* Bbase1 = B1 + (size_t)(n0 + srow) * K1 + sslot * 8;
  char* ldsWaveDst = lds8 + (wv << 10);

  const int swz0 = ((lhi ^ (ln & 7)) << 4);
  const char* aRd0 = lds8 + (wm*64 + llo)*128 + swz0;
  const char* aRd1 = lds8 + (wm*64 + llo)*128 + (swz0 ^ 64);
  const char* bRd0 = lds8 + 65536 + (wn*32 + llo)*128 + swz0;
  const char* bRd1 = lds8 + 65536 + (wn*32 + llo)*128 + (swz0 ^ 64);

  auto ldA = [&](int b, int mf, int ks) -> short8 {
    const char* p = (ks ? aRd1 : aRd0) + b*32768 + (mf>>2)*16384 + (mf&3)*2048;
    return *reinterpret_cast<const short8*>(p);
  };
  auto ldB = [&](int b, int nf, int ks) -> short8 {
    const char* p = (ks ? bRd1 : bRd0) + b*32768 + (nf>>1)*16384 + (nf&1)*2048;
    return *reinterpret_cast<const short8*>(p);
  };

  f32x4 acc[8][4];
  #pragma unroll
  for (int m = 0; m < 8; ++m)
    #pragma unroll
    for (int n = 0; n < 4; ++n) acc[m][n] = 0.0f;

  STAGE(0, 0, 0, 0);
  STAGE(1, 0, 1, 0);
  STAGE(0, 0, 1, 0);
  STAGE(1, 0, 0, 0);
  STAGE(0, 1, 0, 1);
  STAGE(1, 1, 1, 1);
  asm volatile("s_waitcnt vmcnt(4)" ::: "memory");
  asm volatile("s_barrier" ::: "memory");

  short8 av[4][2], b0v[2][2], b1v[2][2];
  #pragma unroll 1
  for (int t0 = 0; t0 < T; t0 += 2){
    TILE(t0,   0);
    TILE(t0+1, 1);
  }

  asm volatile("s_nop 7\n\ts_nop 7\n\ts_nop 7" ::: );

  #pragma unroll
  for (int mf = 0; mf < 8; ++mf){
    const int row = m0 + (mf>>2)*128 + wm*64 + (mf&3)*16 + lhi*4;
    #pragma unroll
    for (int j = 0; j < 4; ++j){
      #pragma unroll
      for (int nf = 0; nf < 4; ++nf){
        const int col = n0 + (nf>>1)*128 + wn*32 + (nf&1)*16 + llo;
        C[(size_t)(row + j) * N + col] = acc[mf][nf][j] + bias[col];
      }
    }
  }
}

// ---------- m97 single-N-tile body (256 active of 512): fc1 / W2q ----------
// C[fb*128.., 0..128) = A@B^T + bias, K=768, bf16 out, swapped epilogue
__device__ __forceinline__
void fc1_body(char* lds, const unsigned short* __restrict__ A,
              const unsigned short* __restrict__ B,
              const float* __restrict__ bias, unsigned short* __restrict__ Cb, int fb)
{
  const int tid = threadIdx.x;
  if (tid >= 256){
    #pragma unroll 1
    for (int i = 0; i < 24; ++i){ __syncthreads(); __syncthreads(); }
    return;
  }
  unsigned short (*sA)[32] = (unsigned short(*)[32])lds;
  unsigned short (*sB)[32] = (unsigned short(*)[32])(lds + 8192);
  const int wv = tid >> 6, ln = tid & 63;
  const int wr = wv >> 1, wc = wv & 1;
  const int lhi = ln >> 4, llo = ln & 15;
  const int m0 = fb * 128;
  const int N = 128, K = 768;

  f32x4 acc[4][4];
  #pragma unroll
  for (int m = 0; m < 4; ++m)
    #pragma unroll
    for (int n = 0; n < 4; ++n) acc[m][n] = 0.0f;

  const int lrow = ln >> 2;
  const int lk8  = (ln & 3) * 8;

  #pragma unroll 1
  for (int kt = 0; kt < 768; kt += 32){
    #pragma unroll
    for (int cc = 0; cc < 2; ++cc){
      int c = wv * 2 + cc;
      gload16(A + (size_t)(m0 + c*16 + lrow) * K + kt + lk8, &sA[c*16][0]);
      gload16(B + (size_t)(c*16 + lrow) * K + kt + lk8, &sB[c*16][0]);
    }
    __syncthreads();

    short8 av[4], bv[4];
    #pragma unroll
    for (int m = 0; m < 4; ++m)
      av[m] = *reinterpret_cast<const short8*>(&sA[wr*64 + m*16 + llo][lhi*8]);
    #pragma unroll
    for (int n = 0; n < 4; ++n)
      bv[n] = *reinterpret_cast<const short8*>(&sB[wc*64 + n*16 + llo][lhi*8]);

    #pragma unroll
    for (int m = 0; m < 4; ++m)
      #pragma unroll
      for (int n = 0; n < 4; ++n)
        mfma16(acc[m][n], bv[n], av[m]);    // SWAPPED: acc = C[m-row][n-cols]
    __syncthreads();
  }

  asm volatile("s_nop 7\n\ts_nop 7\n\ts_nop 7" ::: );

  float4 bias4[4];
  #pragma unroll
  for (int n = 0; n < 4; ++n)
    bias4[n] = *reinterpret_cast<const float4*>(&bias[wc*64 + n*16 + lhi*4]);

  #pragma unroll
  for (int m = 0; m < 4; ++m){
    const int row = m0 + wr*64 + m*16 + llo;
    #pragma unroll
    for (int n = 0; n < 4; ++n){
      const int colbase = wc*64 + n*16 + lhi*4;
      ushort4 o;
      o.x = f2bf(acc[m][n][0] + bias4[n].x);
      o.y = f2bf(acc[m][n][1] + bias4[n].y);
      o.z = f2bf(acc[m][n][2] + bias4[n].z);
      o.w = f2bf(acc[m][n][3] + bias4[n].w);
      *reinterpret_cast<ushort4*>(&Cb[(size_t)row * N + colbase]) = o;
    }
  }
}

// ---------- fc2-for-csim body (256 active of 512): partials only ----------
// A = G [16384][128], B = w2b [768][128], K=128, N=768; v = acc+bias+add;
// writes part[24][16384] (validated EPI1 machinery, no Cb store)
__device__ __forceinline__
void fc2csim_body(char* lds, const unsigned short* __restrict__ A,
                  const unsigned short* __restrict__ B,
                  const float* __restrict__ bias, const unsigned short* __restrict__ addb,
                  const float* __restrict__ meanb, float* __restrict__ part,
                  int bx, int by)
{
  const int tid = threadIdx.x;
  if (tid >= 256){
    #pragma unroll 1
    for (int i = 0; i < 4; ++i){ __syncthreads(); __syncthreads(); }
    return;
  }
  unsigned short (*sA)[32] = (unsigned short(*)[32])lds;
  unsigned short (*sB)[32] = (unsigned short(*)[32])(lds + 8192);
  const int wv = tid >> 6, ln = tid & 63;
  const int wr = wv >> 1, wc = wv & 1;
  const int lhi = ln >> 4, llo = ln & 15;
  const int m0 = bx * 128, n0 = by * 128;
  const int N = CH, K = HIDN;

  f32x4 acc[4][4];
  #pragma unroll
  for (int m = 0; m < 4; ++m)
    #pragma unroll
    for (int n = 0; n < 4; ++n) acc[m][n] = 0.0f;

  const int lrow = ln >> 2;
  const int lk8  = (ln & 3) * 8;

  #pragma unroll 1
  for (int kt = 0; kt < 128; kt += 32){
    #pragma unroll
    for (int cc = 0; cc < 2; ++cc){
      int c = wv * 2 + cc;
      gload16(A + (size_t)(m0 + c*16 + lrow) * K + kt + lk8, &sA[c*16][0]);
      gload16(B + (size_t)(n0 + c*16 + lrow) * K + kt + lk8, &sB[c*16][0]);
    }
    __syncthreads();

    short8 av[4], bv[4];
    #pragma unroll
    for (int m = 0; m < 4; ++m)
      av[m] = *reinterpret_cast<const short8*>(&sA[wr*64 + m*16 + llo][lhi*8]);
    #pragma unroll
    for (int n = 0; n < 4; ++n)
      bv[n] = *reinterpret_cast<const short8*>(&sB[wc*64 + n*16 + llo][lhi*8]);

    #pragma unroll
    for (int m = 0; m < 4; ++m)
      #pragma unroll
      for (int n = 0; n < 4; ++n)
        mfma16(acc[m][n], bv[n], av[m]);    // SWAPPED
    __syncthreads();
  }

  asm volatile("s_nop 7\n\ts_nop 7\n\ts_nop 7" ::: );

  float4 bias4[4];
  #pragma unroll
  for (int n = 0; n < 4; ++n)
    bias4[n] = *reinterpret_cast<const float4*>(&bias[n0 + wc*64 + n*16 + lhi*4]);

  const int bb = m0 >> 10;
  const float* mp = meanb + bb * CH;
  float4 mp4[4];
  #pragma unroll
  for (int n = 0; n < 4; ++n)
    mp4[n] = *reinterpret_cast<const float4*>(&mp[n0 + wc*64 + n*16 + lhi*4]);

  #pragma unroll
  for (int m = 0; m < 4; ++m){
    const int row = m0 + wr*64 + m*16 + llo;
    float dsum = 0.f, qsum = 0.f;
    #pragma unroll
    for (int n = 0; n < 4; ++n){
      const int colbase = n0 + wc*64 + n*16 + lhi*4;
      ushort4 a4 = *reinterpret_cast<const ushort4*>(&addb[(size_t)row * N + colbase]);
      float v0 = acc[m][n][0] + bias4[n].x + bf2f(a4.x);
      float v1 = acc[m][n][1] + bias4[n].y + bf2f(a4.y);
      float v2 = acc[m][n][2] + bias4[n].z + bf2f(a4.z);
      float v3 = acc[m][n][3] + bias4[n].w + bf2f(a4.w);
      dsum += v0*mp4[n].x + v1*mp4[n].y + v2*mp4[n].z + v3*mp4[n].w;
      qsum += v0*v0 + v1*v1 + v2*v2 + v3*v3;
    }
    dsum += __shfl_xor(dsum, 16, 64);  qsum += __shfl_xor(qsum, 16, 64);
    dsum += __shfl_xor(dsum, 32, 64);  qsum += __shfl_xor(qsum, 32, 64);
    if (ln < 16){
      const int slot = by * 2 + wc;            // 0..11
      part[(size_t)slot * MTOT + row] = dsum;
      part[(size_t)(12 + slot) * MTOT + row] = qsum;
    }
  }
}

// ---------- mean body: 512 threads, contiguous bf16 reads ----------
__device__ __forceinline__
void mean_body(char* lds, const unsigned short* __restrict__ x1b,
               float* __restrict__ meanb, float* __restrict__ n1p, int mbid)
{
  float (*tmp)[128] = (float(*)[128])lds;   // [32][128] = 16 KB
  const int b = mbid / 6, cg = mbid % 6;
  const int tid = threadIdx.x;
  const int oct = tid & 15, rg = tid >> 4;
  const unsigned short* ip = x1b + (size_t)b*NT*CH + (size_t)rg*32*CH + cg*128 + oct*8;

  float s[8];
  #pragma unroll
  for (int j = 0; j < 8; ++j) s[j] = 0.f;
  #pragma unroll 4
  for (int r = 0; r < 32; ++r){
    short8 v = *reinterpret_cast<const short8*>(ip + (size_t)r*CH);
    #pragma unroll
    for (int j = 0; j < 8; ++j) s[j] += bf2f((unsigned short)v[j]);
  }
  #pragma unroll
  for (int j = 0; j < 8; ++j) tmp[rg][oct*8 + j] = s[j];
  __syncthreads();

  if (tid < 128){
    float m = 0.f;
    #pragma unroll
    for (int g = 0; g < 32; ++g) m += tmp[g][tid];
    m *= (1.0f/1024.0f);
    meanb[b*CH + cg*128 + tid] = m;
    float q = m * m;
    for (int off = 32; off; off >>= 1) q += __shfl_down(q, off, 64);
    if ((tid & 63) == 0) n1p[b*12 + cg*2 + (tid >> 6)] = q;
  }
}

// ---------- combo 1: q1 (576) | fc1 (128) | mean (96) | W2q (18) ----------
__global__ __launch_bounds__(512, 2)
void k_combo(const unsigned short* __restrict__ x1b, const unsigned short* __restrict__ wqb,
             const float* __restrict__ qkv_b, float* __restrict__ q1,
             const unsigned short* __restrict__ x2b, const unsigned short* __restrict__ w1b,
             const float* __restrict__ fc1_b, unsigned short* __restrict__ t1dst,
             float* __restrict__ meanb, float* __restrict__ n1p,
             const unsigned short* __restrict__ w2tb, const float* __restrict__ z128,
             unsigned short* __restrict__ W2q)
{
  __shared__ __align__(1024) char lds8[131072];
  const int bid = blockIdx.x;
  if (bid < 576){
    gemm256_body<CH/64, CH/64>(lds8, x1b, x1b, wqb, wqb, qkv_b, q1,
                               OUTF, CH, CH, OUTF/256, bid, 576);
  } else if (bid < 704){
    fc1_body(lds8, x2b, w1b, fc1_b, t1dst, bid - 576);
  } else if (bid < 800){
    mean_body(lds8, x1b, meanb, n1p, bid - 704);
  } else {
    fc1_body(lds8, wqb, w2tb, z128, W2q, bid - 800);   // W2q = qkv_w @ fc2_w
  }
}

// ---------- combo 2: q2 concat-GEMM (576) | fc2-csim (768) ----------
__global__ __launch_bounds__(512, 2)
void k_combo2(const unsigned short* __restrict__ x2b, const unsigned short* __restrict__ G,
              const unsigned short* __restrict__ wqb, const unsigned short* __restrict__ W2q,
              const float* __restrict__ qb2, float* __restrict__ q2,
              const unsigned short* __restrict__ w2b, const float* __restrict__ fc2_b,
              const float* __restrict__ meanb, float* __restrict__ part)
{
  __shared__ __align__(1024) char lds8[131072];
  const int bid = blockIdx.x;
  if (bid < 576){
    gemm256_body<14, 12>(lds8, x2b, G, wqb, W2q, qb2, q2,
                         OUTF, CH, HIDN, OUTF/256, bid, 576);
  } else {
    const int idx = bid - 576;        // 0..767 -> 128 x 6
    fc2csim_body(lds8, G, w2b, fc2_b, x2b, meanb, part, idx / 6, idx % 6);
  }
}

// ---------- depthwise 3x3 SAME conv over 32x32 + bias + exact GELU ----------
__global__ void k_dwgelu(const unsigned short* __restrict__ t1b, const float* __restrict__ dww,
                         const float* __restrict__ dwb, unsigned short* __restrict__ t2)
{
  int idx = blockIdx.x * blockDim.x + threadIdx.x;
  int hq = idx & 31; int t = idx >> 5;
  int h = hq * 4;
  int n = t & (NT-1); int b = t >> 10;
  int y = n >> 5, x = n & 31;

  float w[4][9];
  #pragma unroll
  for (int i = 0; i < 4; ++i)
    #pragma unroll
    for (int k = 0; k < 9; ++k) w[i][k] = dww[(h+i)*9 + k];

  float a0 = dwb[h+0], a1 = dwb[h+1], a2 = dwb[h+2], a3 = dwb[h+3];
  #pragma unroll
  for (int dy = -1; dy <= 1; ++dy){
    int yy = y + dy; if ((unsigned)yy >= 32u) continue;
    #pragma unroll
    for (int dx = -1; dx <= 1; ++dx){
      int xx = x + dx; if ((unsigned)xx >= 32u) continue;
      ushort4 v = *reinterpret_cast<const ushort4*>(&t1b[((size_t)b*NT + yy*32 + xx)*HIDN + h]);
      int k = (dy+1)*3 + (dx+1);
      a0 += bf2f(v.x) * w[0][k]; a1 += bf2f(v.y) * w[1][k];
      a2 += bf2f(v.z) * w[2][k]; a3 += bf2f(v.w) * w[3][k];
    }
  }
  const float is2 = 0.70710678118654752440f;
  a0 = 0.5f*a0*(1.0f + erff(a0*is2));
  a1 = 0.5f*a1*(1.0f + erff(a1*is2));
  a2 = 0.5f*a2*(1.0f + erff(a2*is2));
  a3 = 0.5f*a3*(1.0f + erff(a3*is2));
  ushort4 o; o.x = f2bf(a0); o.y = f2bf(a1); o.z = f2bf(a2); o.w = f2bf(a3);
  *reinterpret_cast<ushort4*>(&t2[(size_t)t*HIDN + h]) = o;
}

// ---------- threefry2x32 (JAX), 20 rounds ----------
__device__ __forceinline__ void threefry(unsigned k0, unsigned k1, unsigned x0, unsigned x1,
                                         unsigned& o0, unsigned& o1){
  unsigned ks2 = k0 ^ k1 ^ 0x1BD11BDAu;
  x0 += k0; x1 += k1;
#define TFR(r) { x0 += x1; x1 = (x1 << r) | (x1 >> (32 - r)); x1 ^= x0; }
  TFR(13) TFR(15) TFR(26) TFR(6)  x0 += k1;  x1 += ks2 + 1u;
  TFR(17) TFR(29) TFR(16) TFR(24) x0 += ks2; x1 += k0 + 2u;
  TFR(13) TFR(15) TFR(26) TFR(6)  x0 += k0;  x1 += k1 + 3u;
  TFR(17) TFR(29) TFR(16) TFR(24) x0 += k1;  x1 += ks2 + 4u;
  TFR(13) TFR(15) TFR(26) TFR(6)  x0 += ks2; x1 += k0 + 5u;
#undef TFR
  o0 = x0; o1 = x1;
}

__device__ __forceinline__ float gumbel_from_bits(unsigned bits){
  float f = __uint_as_float((bits >> 9) | 0x3F800000u) - 1.0f;
  const float TINY = 1.17549435e-38f;
  float u = fmaxf(TINY, f + TINY);
  return -logf(-logf(u));
}

// ---------- csim finalize + min/max normalize + router MLP (LDS weights) ----------
__global__ void k_router(const float* __restrict__ part, const float* __restrict__ n1p,
                         const float* __restrict__ r1w, const float* __restrict__ r1b,
                         const float* __restrict__ r2w, const float* __restrict__ r2b,
                         float* __restrict__ out)
{
  int b = blockIdx.x, tid = threadIdx.x;
  __shared__ float cs[NT];
  __shared__ float red[8];
  __shared__ float w1s[HIDN], b1s[HIDN], w20s[HIDN], w21s[HIDN];
  if (tid < HIDN){
    w1s[tid]  = r1w[tid];
    b1s[tid]  = r1b[tid];
    w20s[tid] = r2w[tid];
    w21s[tid] = r2w[HIDN + tid];
  }
  float n1s = 0.f;
  #pragma unroll
  for (int s = 0; s < 12; ++s) n1s += n1p[b*12 + s];
  float n1 = sqrtf(n1s);
  float lmin = 3.4e38f, lmax = -3.4e38f;
  #pragma unroll
  for (int j = 0; j < 4; ++j){
    int tk = tid + j*256;
    int t = b*NT + tk;
    float dot = 0.f, q = 0.f;
    #pragma unroll
    for (int s = 0; s < 12; ++s){
      dot += part[(size_t)s * MTOT + t];
      q   += part[(size_t)(12 + s) * MTOT + t];
    }
    float v = dot / (n1 * sqrtf(q));
    cs[tk] = v;
    lmin = fminf(lmin, v); lmax = fmaxf(lmax, v);
  }
  int ln = tid & 63, wv = tid >> 6;
  for (int off = 32; off; off >>= 1){
    lmin = fminf(lmin, __shfl_down(lmin, off, 64));
    lmax = fmaxf(lmax, __shfl_down(lmax, off, 64));
  }
  if (ln == 0){ red[wv] = lmin; red[4+wv] = lmax; }
  __syncthreads();
  float mn = fminf(fminf(red[0], red[1]), fminf(red[2], red[3]));
  float mx = fmaxf(fmaxf(red[4], red[5]), fmaxf(red[6], red[7]));
  float rng = mx - mn;
  bool nz = (rng != 0.0f);

  const float r2b0 = r2b[0], r2b1 = r2b[1];
  float v[4], l0[4], l1[4];
  #pragma unroll
  for (int j = 0; j < 4; ++j){
    float c0 = cs[tid + j*256];
    v[j] = nz ? (c0 - mn) / rng : c0;
    l0[j] = r2b0; l1[j] = r2b1;
  }
  for (int k = 0; k < HIDN; ++k){
    float a = w1s[k], bb = b1s[k], c0 = w20s[k], c1 = w21s[k];
    #pragma unroll
    for (int j = 0; j < 4; ++j){
      float hh = fmaxf(v[j] * a + bb, 0.f);
      l0[j] += hh * c0;
      l1[j] += hh * c1;
    }
  }
  #pragma unroll
  for (int j = 0; j < 4; ++j){
    float s0 = 1.f / (1.f + expf(-l0[j]));
    float s1 = 1.f / (1.f + expf(-l1[j]));
    int t = b*NT + tid + j*256;
    unsigned o0, o1;
    threefry(0u, 42u, 0u, (unsigned)(2*t),     o0, o1);
    float g0 = gumbel_from_bits(o0 ^ o1);
    threefry(0u, 42u, 0u, (unsigned)(2*t + 1), o0, o1);
    float g1 = gumbel_from_bits(o0 ^ o1);
    out[t] = 1.f / (1.f + expf((s1 + g1) - (s0 + g0)));
  }
}

extern "C" void kernel_launch(void* const* d_in, const int* in_sizes, int n_in,
                              void* d_out, int out_size, void* d_ws, size_t ws_size,
                              hipStream_t stream)
{
  (void)in_sizes; (void)n_in; (void)out_size;
  const float* input  = (const float*)d_in[0];
  const float* input2 = (const float*)d_in[3];
  const float* qkv_w  = (const float*)d_in[4];
  const float* qkv_b  = (const float*)d_in[5];
  const float* fc1_w  = (const float*)d_in[6];
  const float* fc1_b  = (const float*)d_in[7];
  const float* dw_w   = (const float*)d_in[8];
  const float* dw_b   = (const float*)d_in[9];
  const float* fc2_w  = (const float*)d_in[10];
  const float* fc2_b  = (const float*)d_in[11];
  const float* r1_w   = (const float*)d_in[12];
  const float* r1_b   = (const float*)d_in[13];
  const float* r2_w   = (const float*)d_in[14];
  const float* r2_b   = (const float*)d_in[15];

  float* q1 = (float*)d_out;
  float* q2 = q1 + (size_t)MTOT * OUTF;
  float* router = q1 + (size_t)2 * MTOT * OUTF;

  if (ws_size < 67000000u) return;

  char* ws = (char*)d_ws;
  unsigned short* x1b = (unsigned short*)ws; ws += (size_t)MTOT*CH*2;   // input bf16
  unsigned short* x2b = (unsigned short*)ws; ws += (size_t)MTOT*CH*2;   // input2 bf16
  unsigned short* wqb = (unsigned short*)ws; ws += (size_t)OUTF*CH*2;
  unsigned short* w1b = (unsigned short*)ws; ws += (size_t)HIDN*CH*2;
  unsigned short* w2b = (unsigned short*)ws; ws += (size_t)CH*HIDN*2;   // fc2_w bf16 [768][128]
  char*           reg = ws;                  ws += (size_t)MTOT*HIDN*4; // 8 MB multi-use region
  unsigned short* t2  = (unsigned short*)ws; ws += (size_t)MTOT*HIDN*2; // G (gelu out)
  float*          mb  = (float*)ws;          ws += (size_t)BQ*CH*4;
  float*          n1p = (float*)ws;          ws += 1024;

  // region layout (byte offsets): part 0..1.5M | w2tb | W2q | qb2 | z128 | t1dst @4M
  float*          part  = (float*)reg;                              // [24][16384] f32
  unsigned short* w2tb  = (unsigned short*)(reg + 1572864);         // [128][768] bf16
  unsigned short* W2q   = (unsigned short*)(reg + 1769472);         // [2304][128] bf16
  float*          qb2   = (float*)(reg + 2359296);                  // [2304] f32
  float*          z128  = (float*)(reg + 2368512);                  // [128] zeros
  unsigned short* t1dst = (unsigned short*)(reg + 4194304);         // [16384][128] bf16

  // 1) fused grid-stride convert for all 5 tensors
  k_f2bf_all<<<dim3(2048), 256, 0, stream>>>(
      input, input2, qkv_w, fc1_w, fc2_w, x1b, x2b, wqb, w1b, w2b);

  // 1b) prep: qb2 = qkv_b + qkv_w@fc2_b; w2tb = fc2_w^T; z128
  k_prep<<<dim3(26), 256, 0, stream>>>(qkv_w, qkv_b, fc2_w, fc2_b, qb2, w2tb, z128);

  // 2) combo: q1 GEMM | fc1 | mean | W2q = qkv_w@fc2_w
  k_combo<<<dim3(818), 512, 0, stream>>>(
      x1b, wqb, qkv_b, q1, x2b, w1b, fc1_b, t1dst, mb, n1p, w2tb, z128, W2q);

  // 3) depthwise conv + gelu -> G
  k_dwgelu<<<dim3(MTOT*32/256), 256, 0, stream>>>(t1dst, dw_w, dw_b, t2);

  // 4) combo2: q2 = [x2b|G] @ [wqb|W2q]^T + qb2  ||  fc2-csim partials
  k_combo2<<<dim3(1344), 512, 0, stream>>>(
      x2b, t2, wqb, W2q, qb2, q2, w2b, fc2_b, mb, part);

  // 5) router
  k_router<<<dim3(BQ), 256, 0, stream>>>(part, n1p, r1_w, r1_b, r2_w, r2_b, router);
}

// Round 9
// 230.523 us; speedup vs baseline: 1.1623x; 1.1623x over previous
//
#include <hip/hip_runtime.h>
#include <cstdint>
#include <cstddef>

#define BQ 16
#define NT 1024
#define CH 768
#define HIDN 128
#define OUTF 2304
#define MTOT (BQ*NT)   // 16384 tokens

typedef __attribute__((ext_vector_type(4))) float f32x4;
typedef __attribute__((ext_vector_type(8))) short short8;   // 8 x bf16 payload

// ---------- small helpers ----------
__device__ __forceinline__ unsigned short f2bf(float f){
  unsigned u = __float_as_uint(f);
  u += 0x7FFFu + ((u >> 16) & 1u);      // RNE
  return (unsigned short)(u >> 16);
}
__device__ __forceinline__ float bf2f(unsigned short h){
  return __uint_as_float(((unsigned)h) << 16);
}

__device__ __forceinline__ void gload16(const void* g, void* l){
  __builtin_amdgcn_global_load_lds((const __attribute__((address_space(1))) void*)g,
                                   (__attribute__((address_space(3))) void*)l, 16, 0, 0);
}

__device__ __forceinline__ void mfma16(f32x4& d, short8 a, short8 b){
  asm volatile("v_mfma_f32_16x16x32_bf16 %0, %1, %2, %0" : "+v"(d) : "v"(a), "v"(b));
}

// ---------- fused fp32 -> bf16 convert of all 5 tensors (grid-stride) ----------
__global__ void k_f2bf_all(const float* __restrict__ in0, const float* __restrict__ in1,
                           const float* __restrict__ in2, const float* __restrict__ in3,
                           const float* __restrict__ in4,
                           unsigned short* __restrict__ o0, unsigned short* __restrict__ o1,
                           unsigned short* __restrict__ o2, unsigned short* __restrict__ o3,
                           unsigned short* __restrict__ o4)
{
  const long step = (long)2048 * 256 * 4;
  for (long i = (long)(blockIdx.x * 256 + threadIdx.x) * 4; i < 27131904L; i += step){
    const float* s; unsigned short* d; long off;
    if      (i < 12582912L){ s = in0; d = o0; off = i; }
    else if (i < 25165824L){ s = in1; d = o1; off = i - 12582912L; }
    else if (i < 26935296L){ s = in2; d = o2; off = i - 25165824L; }
    else if (i < 27033600L){ s = in3; d = o3; off = i - 26935296L; }
    else                   { s = in4; d = o4; off = i - 27033600L; }
    float4 v = *reinterpret_cast<const float4*>(s + off);
    ushort4 o;
    o.x = f2bf(v.x); o.y = f2bf(v.y); o.z = f2bf(v.z); o.w = f2bf(v.w);
    *reinterpret_cast<ushort4*>(d + off) = o;
  }
}

// ============================================================================
// 256x256 8-phase GEMM body (T1+T2+T3+T4+T5) — r3/r5/r7-validated
// ============================================================================
#define STAGE(matB_, buf_, h_, t_) { \
    const unsigned short* g_ = ((matB_) ? Bbase : Abase) + (size_t)(h_)*128*K + (size_t)(t_)*64; \
    char* d_ = ldsWaveDst + (matB_)*65536 + (buf_)*32768 + (h_)*16384; \
    gload16(g_, d_); \
    gload16(g_ + rowK64, d_ + 8192); \
  }

#define PH_OPEN() \
    asm volatile("s_barrier" ::: "memory"); \
    asm volatile("s_waitcnt lgkmcnt(0)" ::: "memory"); \
    __builtin_amdgcn_sched_barrier(0); \
    __builtin_amdgcn_s_setprio(1);

#define PH_CLOSE() \
    __builtin_amdgcn_s_setprio(0); \
    asm volatile("s_barrier" ::: "memory");

#define MF16(mb, nb, BV) \
    _Pragma("unroll") \
    for (int ks = 0; ks < 2; ++ks) \
      _Pragma("unroll") \
      for (int mf = 0; mf < 4; ++mf) \
        _Pragma("unroll") \
        for (int nf = 0; nf < 2; ++nf) \
          mfma16(acc[(mb)+mf][(nb)+nf], av[mf][ks], BV[nf][ks]);

#define TILE(t_, b_) { \
    const int t = (t_); const int b = (b_); \
    _Pragma("unroll") for (int mf = 0; mf < 4; ++mf){ av[mf][0]=ldA(b,mf,0); av[mf][1]=ldA(b,mf,1); } \
    _Pragma("unroll") for (int nf = 0; nf < 2; ++nf){ b0v[nf][0]=ldB(b,nf,0); b0v[nf][1]=ldB(b,nf,1); } \
    if (t+1 < T) STAGE(0, b^1, 1, t+1); \
    PH_OPEN(); MF16(0,0,b0v); PH_CLOSE(); \
    _Pragma("unroll") for (int nf = 0; nf < 2; ++nf){ b1v[nf][0]=ldB(b,2+nf,0); b1v[nf][1]=ldB(b,2+nf,1); } \
    if (t+1 < T) STAGE(1, b^1, 0, t+1); \
    PH_OPEN(); MF16(0,2,b1v); PH_CLOSE(); \
    _Pragma("unroll") for (int mf = 0; mf < 4; ++mf){ av[mf][0]=ldA(b,4+mf,0); av[mf][1]=ldA(b,4+mf,1); } \
    if (t+2 < T) STAGE(0, b, 0, t+2); \
    PH_OPEN(); MF16(4,2,b1v); PH_CLOSE(); \
    if (t+2 < T) STAGE(1, b, 1, t+2); \
    PH_OPEN(); MF16(4,0,b0v); \
    __builtin_amdgcn_s_setprio(0); \
    if (t+2 < T) { asm volatile("s_waitcnt vmcnt(4)" ::: "memory"); } \
    else         { asm volatile("s_waitcnt vmcnt(0)" ::: "memory"); } \
    asm volatile("s_barrier" ::: "memory"); \
  }

template<int T>   // K = T*64, T even
__device__ __forceinline__
void gemm256_body(char* lds8,
                  const unsigned short* __restrict__ A,
                  const unsigned short* __restrict__ B,
                  const float* __restrict__ bias,
                  float* __restrict__ C,
                  int N, int K, int nbn, int bid, int nwg)
{
  const int tid = threadIdx.x;
  const int ln = tid & 63, wv = tid >> 6;
  const int wm = wv >> 2, wn = wv & 3;
  const int llo = ln & 15, lhi = ln >> 4;

  const int cpx = nwg >> 3;
  const int swz = (bid & 7) * cpx + (bid >> 3);
  const int bm = swz / nbn, bn = swz % nbn;
  const int m0 = bm * 256, n0 = bn * 256;

  const int srow = tid >> 3;
  const int sslot = (tid & 7) ^ (srow & 7);
  const unsigned short* Abase = A + (size_t)(m0 + srow) * K + sslot * 8;
  const unsigned short* Bbase = B + (size_t)(n0 + srow) * K + sslot * 8;
  const size_t rowK64 = (size_t)64 * K;
  char* ldsWaveDst = lds8 + (wv << 10);

  const int swz0 = ((lhi ^ (ln & 7)) << 4);
  const char* aRd0 = lds8 + (wm*64 + llo)*128 + swz0;
  const char* aRd1 = lds8 + (wm*64 + llo)*128 + (swz0 ^ 64);
  const char* bRd0 = lds8 + 65536 + (wn*32 + llo)*128 + swz0;
  const char* bRd1 = lds8 + 65536 + (wn*32 + llo)*128 + (swz0 ^ 64);

  auto ldA = [&](int b, int mf, int ks) -> short8 {
    const char* p = (ks ? aRd1 : aRd0) + b*32768 + (mf>>2)*16384 + (mf&3)*2048;
    return *reinterpret_cast<const short8*>(p);
  };
  auto ldB = [&](int b, int nf, int ks) -> short8 {
    const char* p = (ks ? bRd1 : bRd0) + b*32768 + (nf>>1)*16384 + (nf&1)*2048;
    return *reinterpret_cast<const short8*>(p);
  };

  f32x4 acc[8][4];
  #pragma unroll
  for (int m = 0; m < 8; ++m)
    #pragma unroll
    for (int n = 0; n < 4; ++n) acc[m][n] = 0.0f;

  STAGE(0, 0, 0, 0);
  STAGE(1, 0, 1, 0);
  STAGE(0, 0, 1, 0);
  STAGE(1, 0, 0, 0);
  STAGE(0, 1, 0, 1);
  STAGE(1, 1, 1, 1);
  asm volatile("s_waitcnt vmcnt(4)" ::: "memory");
  asm volatile("s_barrier" ::: "memory");

  short8 av[4][2], b0v[2][2], b1v[2][2];
  #pragma unroll 1
  for (int t0 = 0; t0 < T; t0 += 2){
    TILE(t0,   0);
    TILE(t0+1, 1);
  }

  asm volatile("s_nop 7\n\ts_nop 7\n\ts_nop 7" ::: );

  #pragma unroll
  for (int mf = 0; mf < 8; ++mf){
    const int row = m0 + (mf>>2)*128 + wm*64 + (mf&3)*16 + lhi*4;
    #pragma unroll
    for (int j = 0; j < 4; ++j){
      #pragma unroll
      for (int nf = 0; nf < 4; ++nf){
        const int col = n0 + (nf>>1)*128 + wn*32 + (nf&1)*16 + llo;
        C[(size_t)(row + j) * N + col] = acc[mf][nf][j] + bias[col];
      }
    }
  }
}

// ---------- fc1 body: m97-structure, 256 active threads of 512 ----------
__device__ __forceinline__
void fc1_body(char* lds, const unsigned short* __restrict__ A,
              const unsigned short* __restrict__ B,
              const float* __restrict__ bias, unsigned short* __restrict__ Cb, int fb)
{
  const int tid = threadIdx.x;
  if (tid >= 256){
    #pragma unroll 1
    for (int i = 0; i < 24; ++i){ __syncthreads(); __syncthreads(); }
    return;
  }
  unsigned short (*sA)[32] = (unsigned short(*)[32])lds;
  unsigned short (*sB)[32] = (unsigned short(*)[32])(lds + 8192);
  const int wv = tid >> 6, ln = tid & 63;
  const int wr = wv >> 1, wc = wv & 1;
  const int lhi = ln >> 4, llo = ln & 15;
  const int m0 = fb * 128;
  const int N = 128, K = 768;

  f32x4 acc[4][4];
  #pragma unroll
  for (int m = 0; m < 4; ++m)
    #pragma unroll
    for (int n = 0; n < 4; ++n) acc[m][n] = 0.0f;

  const int lrow = ln >> 2;
  const int lk8  = (ln & 3) * 8;

  #pragma unroll 1
  for (int kt = 0; kt < 768; kt += 32){
    #pragma unroll
    for (int cc = 0; cc < 2; ++cc){
      int c = wv * 2 + cc;
      gload16(A + (size_t)(m0 + c*16 + lrow) * K + kt + lk8, &sA[c*16][0]);
      gload16(B + (size_t)(c*16 + lrow) * K + kt + lk8, &sB[c*16][0]);
    }
    __syncthreads();

    short8 av[4], bv[4];
    #pragma unroll
    for (int m = 0; m < 4; ++m)
      av[m] = *reinterpret_cast<const short8*>(&sA[wr*64 + m*16 + llo][lhi*8]);
    #pragma unroll
    for (int n = 0; n < 4; ++n)
      bv[n] = *reinterpret_cast<const short8*>(&sB[wc*64 + n*16 + llo][lhi*8]);

    #pragma unroll
    for (int m = 0; m < 4; ++m)
      #pragma unroll
      for (int n = 0; n < 4; ++n)
        mfma16(acc[m][n], bv[n], av[m]);    // SWAPPED: acc = C[m-row][n-cols]
    __syncthreads();
  }

  asm volatile("s_nop 7\n\ts_nop 7\n\ts_nop 7" ::: );

  float4 bias4[4];
  #pragma unroll
  for (int n = 0; n < 4; ++n)
    bias4[n] = *reinterpret_cast<const float4*>(&bias[wc*64 + n*16 + lhi*4]);

  #pragma unroll
  for (int m = 0; m < 4; ++m){
    const int row = m0 + wr*64 + m*16 + llo;
    #pragma unroll
    for (int n = 0; n < 4; ++n){
      const int colbase = wc*64 + n*16 + lhi*4;
      ushort4 o;
      o.x = f2bf(acc[m][n][0] + bias4[n].x);
      o.y = f2bf(acc[m][n][1] + bias4[n].y);
      o.z = f2bf(acc[m][n][2] + bias4[n].z);
      o.w = f2bf(acc[m][n][3] + bias4[n].w);
      *reinterpret_cast<ushort4*>(&Cb[(size_t)row * N + colbase]) = o;
    }
  }
}

// ---------- mean body: 512 threads, contiguous bf16 reads ----------
__device__ __forceinline__
void mean_body(char* lds, const unsigned short* __restrict__ x1b,
               float* __restrict__ meanb, float* __restrict__ n1p, int mbid)
{
  float (*tmp)[128] = (float(*)[128])lds;   // [32][128] = 16 KB
  const int b = mbid / 6, cg = mbid % 6;
  const int tid = threadIdx.x;
  const int oct = tid & 15, rg = tid >> 4;
  const unsigned short* ip = x1b + (size_t)b*NT*CH + (size_t)rg*32*CH + cg*128 + oct*8;

  float s[8];
  #pragma unroll
  for (int j = 0; j < 8; ++j) s[j] = 0.f;
  #pragma unroll 4
  for (int r = 0; r < 32; ++r){
    short8 v = *reinterpret_cast<const short8*>(ip + (size_t)r*CH);
    #pragma unroll
    for (int j = 0; j < 8; ++j) s[j] += bf2f((unsigned short)v[j]);
  }
  #pragma unroll
  for (int j = 0; j < 8; ++j) tmp[rg][oct*8 + j] = s[j];
  __syncthreads();

  if (tid < 128){
    float m = 0.f;
    #pragma unroll
    for (int g = 0; g < 32; ++g) m += tmp[g][tid];
    m *= (1.0f/1024.0f);
    meanb[b*CH + cg*128 + tid] = m;
    float q = m * m;
    for (int off = 32; off; off >>= 1) q += __shfl_down(q, off, 64);
    if ((tid & 63) == 0) n1p[b*12 + cg*2 + (tid >> 6)] = q;
  }
}

// ---------- threefry2x32 (JAX), 20 rounds ----------
__device__ __forceinline__ void threefry(unsigned k0, unsigned k1, unsigned x0, unsigned x1,
                                         unsigned& o0, unsigned& o1){
  unsigned ks2 = k0 ^ k1 ^ 0x1BD11BDAu;
  x0 += k0; x1 += k1;
#define TFR(r) { x0 += x1; x1 = (x1 << r) | (x1 >> (32 - r)); x1 ^= x0; }
  TFR(13) TFR(15) TFR(26) TFR(6)  x0 += k1;  x1 += ks2 + 1u;
  TFR(17) TFR(29) TFR(16) TFR(24) x0 += ks2; x1 += k0 + 2u;
  TFR(13) TFR(15) TFR(26) TFR(6)  x0 += k0;  x1 += k1 + 3u;
  TFR(17) TFR(29) TFR(16) TFR(24) x0 += k1;  x1 += ks2 + 4u;
  TFR(13) TFR(15) TFR(26) TFR(6)  x0 += ks2; x1 += k0 + 5u;
#undef TFR
  o0 = x0; o1 = x1;
}

__device__ __forceinline__ float gumbel_from_bits(unsigned bits){
  float f = __uint_as_float((bits >> 9) | 0x3F800000u) - 1.0f;
  const float TINY = 1.17549435e-38f;
  float u = fmaxf(TINY, f + TINY);
  return -logf(-logf(u));
}

// ---------- router body: 512 threads, 2 tokens each; 1 barrier ----------
__device__ __forceinline__
void router_body(char* lds, const float* __restrict__ part, const float* __restrict__ n1p,
                 const float* __restrict__ r1w, const float* __restrict__ r1b,
                 const float* __restrict__ r2w, const float* __restrict__ r2b,
                 float* __restrict__ out, int b)
{
  float* cs   = (float*)lds;                 // [1024]
  float* red  = (float*)(lds + 4096);        // [16]
  float* w1s  = (float*)(lds + 4096 + 64);   // [128] x4
  float* b1s  = w1s + HIDN;
  float* w20s = b1s + HIDN;
  float* w21s = w20s + HIDN;
  const int tid = threadIdx.x;
  if (tid < HIDN){
    w1s[tid]  = r1w[tid];
    b1s[tid]  = r1b[tid];
    w20s[tid] = r2w[tid];
    w21s[tid] = r2w[HIDN + tid];
  }
  float n1s = 0.f;
  #pragma unroll
  for (int s = 0; s < 12; ++s) n1s += n1p[b*12 + s];
  float n1 = sqrtf(n1s);
  float lmin = 3.4e38f, lmax = -3.4e38f;
  #pragma unroll
  for (int j = 0; j < 2; ++j){
    int tk = tid + j*512;
    int t = b*NT + tk;
    float dot = 0.f, q = 0.f;
    #pragma unroll
    for (int s = 0; s < 12; ++s){
      dot += part[(size_t)s * MTOT + t];
      q   += part[(size_t)(12 + s) * MTOT + t];
    }
    float v = dot / (n1 * sqrtf(q));
    cs[tk] = v;
    lmin = fminf(lmin, v); lmax = fmaxf(lmax, v);
  }
  int ln = tid & 63, wv = tid >> 6;
  for (int off = 32; off; off >>= 1){
    lmin = fminf(lmin, __shfl_down(lmin, off, 64));
    lmax = fmaxf(lmax, __shfl_down(lmax, off, 64));
  }
  if (ln == 0){ red[wv] = lmin; red[8+wv] = lmax; }
  __syncthreads();
  float mn = red[0], mx = red[8];
  #pragma unroll
  for (int s = 1; s < 8; ++s){ mn = fminf(mn, red[s]); mx = fmaxf(mx, red[8+s]); }
  float rng = mx - mn;
  bool nz = (rng != 0.0f);

  const float r2b0 = r2b[0], r2b1 = r2b[1];
  float v[2], l0[2], l1[2];
  #pragma unroll
  for (int j = 0; j < 2; ++j){
    float c0 = cs[tid + j*512];
    v[j] = nz ? (c0 - mn) / rng : c0;
    l0[j] = r2b0; l1[j] = r2b1;
  }
  for (int k = 0; k < HIDN; ++k){
    float a = w1s[k], bb = b1s[k], c0 = w20s[k], c1 = w21s[k];
    #pragma unroll
    for (int j = 0; j < 2; ++j){
      float hh = fmaxf(v[j] * a + bb, 0.f);
      l0[j] += hh * c0;
      l1[j] += hh * c1;
    }
  }
  #pragma unroll
  for (int j = 0; j < 2; ++j){
    float s0 = 1.f / (1.f + expf(-l0[j]));
    float s1 = 1.f / (1.f + expf(-l1[j]));
    int t = b*NT + tid + j*512;
    unsigned o0, o1;
    threefry(0u, 42u, 0u, (unsigned)(2*t),     o0, o1);
    float g0 = gumbel_from_bits(o0 ^ o1);
    threefry(0u, 42u, 0u, (unsigned)(2*t + 1), o0, o1);
    float g1 = gumbel_from_bits(o0 ^ o1);
    out[t] = 1.f / (1.f + expf((s1 + g1) - (s0 + g0)));
  }
}

// ---------- combo 1: q1 (576) | fc1 (128) | mean (96) ----------
__global__ __launch_bounds__(512, 2)
void k_combo(const unsigned short* __restrict__ x1b, const unsigned short* __restrict__ wqb,
             const float* __restrict__ qkv_b, float* __restrict__ q1,
             const unsigned short* __restrict__ xrb, const unsigned short* __restrict__ w1b,
             const float* __restrict__ fc1_b, unsigned short* __restrict__ t1dst,
             float* __restrict__ meanb, float* __restrict__ n1p)
{
  __shared__ __align__(1024) char lds8[131072];
  const int bid = blockIdx.x;
  if (bid < 576){
    gemm256_body<CH/64>(lds8, x1b, wqb, qkv_b, q1, OUTF, CH, OUTF/256, bid, 576);
  } else if (bid < 704){
    fc1_body(lds8, xrb, w1b, fc1_b, t1dst, bid - 576);
  } else {
    mean_body(lds8, x1b, meanb, n1p, bid - 704);
  }
}

// ---------- combo 2: q2 GEMM (576) | router (16) ----------
__global__ __launch_bounds__(512, 2)
void k_combo2(const unsigned short* __restrict__ xrb, const unsigned short* __restrict__ wqb,
              const float* __restrict__ qkv_b, float* __restrict__ q2,
              const float* __restrict__ part, const float* __restrict__ n1p,
              const float* __restrict__ r1w, const float* __restrict__ r1b,
              const float* __restrict__ r2w, const float* __restrict__ r2b,
              float* __restrict__ router)
{
  __shared__ __align__(1024) char lds8[131072];
  const int bid = blockIdx.x;
  if (bid < 576){
    gemm256_body<CH/64>(lds8, xrb, wqb, qkv_b, q2, OUTF, CH, OUTF/256, bid, 576);
  } else {
    router_body(lds8, part, n1p, r1w, r1b, r2w, r2b, router, bid - 576);
  }
}

// ---------- m97-structure MFMA GEMM, fc2 (EPI1): refine + csim partials ----------
__global__ __launch_bounds__(256, 2)
void k_gemm_fc2(const unsigned short* __restrict__ A, const unsigned short* __restrict__ B,
                const float* __restrict__ bias, const unsigned short* __restrict__ addb,
                unsigned short* __restrict__ Cb,
                const float* __restrict__ meanb, float* __restrict__ part,
                int M, int N, int K)
{
  __shared__ unsigned short sA[128][32];
  __shared__ unsigned short sB[128][32];
  const int tid = threadIdx.x;
  const int wv = tid >> 6, ln = tid & 63;
  const int wr = wv >> 1, wc = wv & 1;
  const int lhi = ln >> 4, llo = ln & 15;
  const int m0 = blockIdx.x * 128, n0 = blockIdx.y * 128;

  f32x4 acc[4][4];
  #pragma unroll
  for (int m = 0; m < 4; ++m)
    #pragma unroll
    for (int n = 0; n < 4; ++n) acc[m][n] = 0.0f;

  const int lrow = ln >> 2;
  const int lk8  = (ln & 3) * 8;

  for (int kt = 0; kt < K; kt += 32){
    #pragma unroll
    for (int cc = 0; cc < 2; ++cc){
      int c = wv * 2 + cc;
      gload16(A + (size_t)(m0 + c*16 + lrow) * K + kt + lk8, &sA[c*16][0]);
      gload16(B + (size_t)(n0 + c*16 + lrow) * K + kt + lk8, &sB[c*16][0]);
    }
    __syncthreads();

    short8 av[4], bv[4];
    #pragma unroll
    for (int m = 0; m < 4; ++m)
      av[m] = *reinterpret_cast<const short8*>(&sA[wr*64 + m*16 + llo][lhi*8]);
    #pragma unroll
    for (int n = 0; n < 4; ++n)
      bv[n] = *reinterpret_cast<const short8*>(&sB[wc*64 + n*16 + llo][lhi*8]);

    #pragma unroll
    for (int m = 0; m < 4; ++m)
      #pragma unroll
      for (int n = 0; n < 4; ++n)
        mfma16(acc[m][n], bv[n], av[m]);    // SWAPPED
    __syncthreads();
  }

  asm volatile("s_nop 7\n\ts_nop 7\n\ts_nop 7" ::: );

  float4 bias4[4];
  #pragma unroll
  for (int n = 0; n < 4; ++n)
    bias4[n] = *reinterpret_cast<const float4*>(&bias[n0 + wc*64 + n*16 + lhi*4]);

  const int bb = m0 >> 10;
  const float* mp = meanb + bb * CH;
  float4 mp4[4];
  #pragma unroll
  for (int n = 0; n < 4; ++n)
    mp4[n] = *reinterpret_cast<const float4*>(&mp[n0 + wc*64 + n*16 + lhi*4]);

  #pragma unroll
  for (int m = 0; m < 4; ++m){
    const int row = m0 + wr*64 + m*16 + llo;
    float dsum = 0.f, qsum = 0.f;
    #pragma unroll
    for (int n = 0; n < 4; ++n){
      const int colbase = n0 + wc*64 + n*16 + lhi*4;
      ushort4 a4 = *reinterpret_cast<const ushort4*>(&addb[(size_t)row * N + colbase]);
      float v0 = acc[m][n][0] + bias4[n].x + bf2f(a4.x);
      float v1 = acc[m][n][1] + bias4[n].y + bf2f(a4.y);
      float v2 = acc[m][n][2] + bias4[n].z + bf2f(a4.z);
      float v3 = acc[m][n][3] + bias4[n].w + bf2f(a4.w);
      ushort4 o; o.x = f2bf(v0); o.y = f2bf(v1); o.z = f2bf(v2); o.w = f2bf(v3);
      *reinterpret_cast<ushort4*>(&Cb[(size_t)row * N + colbase]) = o;
      dsum += v0*mp4[n].x + v1*mp4[n].y + v2*mp4[n].z + v3*mp4[n].w;
      qsum += v0*v0 + v1*v1 + v2*v2 + v3*v3;
    }
    dsum += __shfl_xor(dsum, 16, 64);  qsum += __shfl_xor(qsum, 16, 64);
    dsum += __shfl_xor(dsum, 32, 64);  qsum += __shfl_xor(qsum, 32, 64);
    if (ln < 16){
      const int slot = blockIdx.y * 2 + wc;            // 0..11
      part[(size_t)slot * MTOT + row] = dsum;
      part[(size_t)(12 + slot) * MTOT + row] = qsum;
    }
  }
}

// ---------- depthwise 3x3 SAME conv over 32x32 + bias + exact GELU (bf16) ----------
__global__ void k_dwgelu(const unsigned short* __restrict__ t1b, const float* __restrict__ dww,
                         const float* __restrict__ dwb, unsigned short* __restrict__ t2)
{
  int idx = blockIdx.x * blockDim.x + threadIdx.x;
  int hq = idx & 31; int t = idx >> 5;
  int h = hq * 4;
  int n = t & (NT-1); int b = t >> 10;
  int y = n >> 5, x = n & 31;

  float w[4][9];
  #pragma unroll
  for (int i = 0; i < 4; ++i)
    #pragma unroll
    for (int k = 0; k < 9; ++k) w[i][k] = dww[(h+i)*9 + k];

  float a0 = dwb[h+0], a1 = dwb[h+1], a2 = dwb[h+2], a3 = dwb[h+3];
  #pragma unroll
  for (int dy = -1; dy <= 1; ++dy){
    int yy = y + dy; if ((unsigned)yy >= 32u) continue;
    #pragma unroll
    for (int dx = -1; dx <= 1; ++dx){
      int xx = x + dx; if ((unsigned)xx >= 32u) continue;
      ushort4 v = *reinterpret_cast<const ushort4*>(&t1b[((size_t)b*NT + yy*32 + xx)*HIDN + h]);
      int k = (dy+1)*3 + (dx+1);
      a0 += bf2f(v.x) * w[0][k]; a1 += bf2f(v.y) * w[1][k];
      a2 += bf2f(v.z) * w[2][k]; a3 += bf2f(v.w) * w[3][k];
    }
  }
  const float is2 = 0.70710678118654752440f;
  a0 = 0.5f*a0*(1.0f + erff(a0*is2));
  a1 = 0.5f*a1*(1.0f + erff(a1*is2));
  a2 = 0.5f*a2*(1.0f + erff(a2*is2));
  a3 = 0.5f*a3*(1.0f + erff(a3*is2));
  ushort4 o; o.x = f2bf(a0); o.y = f2bf(a1); o.z = f2bf(a2); o.w = f2bf(a3);
  *reinterpret_cast<ushort4*>(&t2[(size_t)t*HIDN + h]) = o;
}

extern "C" void kernel_launch(void* const* d_in, const int* in_sizes, int n_in,
                              void* d_out, int out_size, void* d_ws, size_t ws_size,
                              hipStream_t stream)
{
  (void)in_sizes; (void)n_in; (void)out_size;
  const float* input  = (const float*)d_in[0];
  const float* input2 = (const float*)d_in[3];
  const float* qkv_w  = (const float*)d_in[4];
  const float* qkv_b  = (const float*)d_in[5];
  const float* fc1_w  = (const float*)d_in[6];
  const float* fc1_b  = (const float*)d_in[7];
  const float* dw_w   = (const float*)d_in[8];
  const float* dw_b   = (const float*)d_in[9];
  const float* fc2_w  = (const float*)d_in[10];
  const float* fc2_b  = (const float*)d_in[11];
  const float* r1_w   = (const float*)d_in[12];
  const float* r1_b   = (const float*)d_in[13];
  const float* r2_w   = (const float*)d_in[14];
  const float* r2_b   = (const float*)d_in[15];

  float* q1 = (float*)d_out;
  float* q2 = q1 + (size_t)MTOT * OUTF;
  float* router = q1 + (size_t)2 * MTOT * OUTF;

  if (ws_size < 67000000u) return;

  char* ws = (char*)d_ws;
  unsigned short* x1b = (unsigned short*)ws; ws += (size_t)MTOT*CH*2;   // input bf16
  unsigned short* xrb = (unsigned short*)ws; ws += (size_t)MTOT*CH*2;   // input2 -> refine bf16
  unsigned short* wqb = (unsigned short*)ws; ws += (size_t)OUTF*CH*2;
  unsigned short* w1b = (unsigned short*)ws; ws += (size_t)HIDN*CH*2;
  unsigned short* w2b = (unsigned short*)ws; ws += (size_t)CH*HIDN*2;
  unsigned short* t1b = (unsigned short*)ws; ws += (size_t)MTOT*HIDN*4; // 8MB region: part | t1dst
  unsigned short* t2  = (unsigned short*)ws; ws += (size_t)MTOT*HIDN*2;
  float*          mb  = (float*)ws;          ws += (size_t)BQ*CH*4;
  float*          n1p = (float*)ws;          ws += 1024;               // [16][12] partials
  float*          part= (float*)t1b;         // csim partials [24][16384] alias region

  // 1) fused grid-stride convert for all 5 tensors
  k_f2bf_all<<<dim3(2048), 256, 0, stream>>>(
      input, input2, qkv_w, fc1_w, fc2_w, x1b, xrb, wqb, w1b, w2b);

  // 2) combo: q1 GEMM (576 blocks) | fc1 (128) | mean (96)
  unsigned short* t1dst = t1b + (size_t)MTOT*HIDN;  // upper half of region
  k_combo<<<dim3(800), 512, 0, stream>>>(
      x1b, wqb, qkv_b, q1, xrb, w1b, fc1_b, t1dst, mb, n1p);

  // 3) depthwise conv + gelu -> t2 bf16
  k_dwgelu<<<dim3(MTOT*32/256), 256, 0, stream>>>(t1dst, dw_w, dw_b, t2);

  // 4) fc2 + input2(bf16) add -> refine bf16 (into xrb) + csim partials -> part
  k_gemm_fc2<<<dim3(MTOT/128, CH/128), 256, 0, stream>>>(
      t2, w2b, fc2_b, xrb, xrb, mb, part, MTOT, CH, HIDN);

  // 5) combo2: q2 GEMM (576) | router (16)
  k_combo2<<<dim3(592), 512, 0, stream>>>(
      xrb, wqb, qkv_b, q2, part, n1p, r1_w, r1_b, r2_w, r2_b, router);
}

// Round 10
// 227.151 us; speedup vs baseline: 1.1796x; 1.0148x over previous
//
#include <hip/hip_runtime.h>
#include <cstdint>
#include <cstddef>

#define BQ 16
#define NT 1024
#define CH 768
#define HIDN 128
#define OUTF 2304
#define MTOT (BQ*NT)   // 16384 tokens

typedef __attribute__((ext_vector_type(4))) float f32x4;
typedef __attribute__((ext_vector_type(8))) short short8;   // 8 x bf16 payload

// ---------- small helpers ----------
__device__ __forceinline__ unsigned short f2bf(float f){
  unsigned u = __float_as_uint(f);
  u += 0x7FFFu + ((u >> 16) & 1u);      // RNE
  return (unsigned short)(u >> 16);
}
__device__ __forceinline__ float bf2f(unsigned short h){
  return __uint_as_float(((unsigned)h) << 16);
}

__device__ __forceinline__ void gload16(const void* g, void* l){
  __builtin_amdgcn_global_load_lds((const __attribute__((address_space(1))) void*)g,
                                   (__attribute__((address_space(3))) void*)l, 16, 0, 0);
}

__device__ __forceinline__ void mfma16(f32x4& d, short8 a, short8 b){
  asm volatile("v_mfma_f32_16x16x32_bf16 %0, %1, %2, %0" : "+v"(d) : "v"(a), "v"(b));
}

// ---------- fused fp32 -> bf16 convert of all 5 tensors (grid-stride) ----------
__global__ void k_f2bf_all(const float* __restrict__ in0, const float* __restrict__ in1,
                           const float* __restrict__ in2, const float* __restrict__ in3,
                           const float* __restrict__ in4,
                           unsigned short* __restrict__ o0, unsigned short* __restrict__ o1,
                           unsigned short* __restrict__ o2, unsigned short* __restrict__ o3,
                           unsigned short* __restrict__ o4)
{
  const long step = (long)2048 * 256 * 4;
  for (long i = (long)(blockIdx.x * 256 + threadIdx.x) * 4; i < 27131904L; i += step){
    const float* s; unsigned short* d; long off;
    if      (i < 12582912L){ s = in0; d = o0; off = i; }
    else if (i < 25165824L){ s = in1; d = o1; off = i - 12582912L; }
    else if (i < 26935296L){ s = in2; d = o2; off = i - 25165824L; }
    else if (i < 27033600L){ s = in3; d = o3; off = i - 26935296L; }
    else                   { s = in4; d = o4; off = i - 27033600L; }
    float4 v = *reinterpret_cast<const float4*>(s + off);
    ushort4 o;
    o.x = f2bf(v.x); o.y = f2bf(v.y); o.z = f2bf(v.z); o.w = f2bf(v.w);
    *reinterpret_cast<ushort4*>(d + off) = o;
  }
}

// ============================================================================
// 256x256 8-phase GEMM body (T1+T2+T3+T4+T5) — r3/r5/r7/r9-validated
// ============================================================================
#define STAGE(matB_, buf_, h_, t_) { \
    const unsigned short* g_ = ((matB_) ? Bbase : Abase) + (size_t)(h_)*128*K + (size_t)(t_)*64; \
    char* d_ = ldsWaveDst + (matB_)*65536 + (buf_)*32768 + (h_)*16384; \
    gload16(g_, d_); \
    gload16(g_ + rowK64, d_ + 8192); \
  }

#define PH_OPEN() \
    asm volatile("s_barrier" ::: "memory"); \
    asm volatile("s_waitcnt lgkmcnt(0)" ::: "memory"); \
    __builtin_amdgcn_sched_barrier(0); \
    __builtin_amdgcn_s_setprio(1);

#define PH_CLOSE() \
    __builtin_amdgcn_s_setprio(0); \
    asm volatile("s_barrier" ::: "memory");

#define MF16(mb, nb, BV) \
    _Pragma("unroll") \
    for (int ks = 0; ks < 2; ++ks) \
      _Pragma("unroll") \
      for (int mf = 0; mf < 4; ++mf) \
        _Pragma("unroll") \
        for (int nf = 0; nf < 2; ++nf) \
          mfma16(acc[(mb)+mf][(nb)+nf], av[mf][ks], BV[nf][ks]);

#define TILE(t_, b_) { \
    const int t = (t_); const int b = (b_); \
    _Pragma("unroll") for (int mf = 0; mf < 4; ++mf){ av[mf][0]=ldA(b,mf,0); av[mf][1]=ldA(b,mf,1); } \
    _Pragma("unroll") for (int nf = 0; nf < 2; ++nf){ b0v[nf][0]=ldB(b,nf,0); b0v[nf][1]=ldB(b,nf,1); } \
    if (t+1 < T) STAGE(0, b^1, 1, t+1); \
    PH_OPEN(); MF16(0,0,b0v); PH_CLOSE(); \
    _Pragma("unroll") for (int nf = 0; nf < 2; ++nf){ b1v[nf][0]=ldB(b,2+nf,0); b1v[nf][1]=ldB(b,2+nf,1); } \
    if (t+1 < T) STAGE(1, b^1, 0, t+1); \
    PH_OPEN(); MF16(0,2,b1v); PH_CLOSE(); \
    _Pragma("unroll") for (int mf = 0; mf < 4; ++mf){ av[mf][0]=ldA(b,4+mf,0); av[mf][1]=ldA(b,4+mf,1); } \
    if (t+2 < T) STAGE(0, b, 0, t+2); \
    PH_OPEN(); MF16(4,2,b1v); PH_CLOSE(); \
    if (t+2 < T) STAGE(1, b, 1, t+2); \
    PH_OPEN(); MF16(4,0,b0v); \
    __builtin_amdgcn_s_setprio(0); \
    if (t+2 < T) { asm volatile("s_waitcnt vmcnt(4)" ::: "memory"); } \
    else         { asm volatile("s_waitcnt vmcnt(0)" ::: "memory"); } \
    asm volatile("s_barrier" ::: "memory"); \
  }

template<int T>   // K = T*64, T even
__device__ __forceinline__
void gemm256_body(char* lds8,
                  const unsigned short* __restrict__ A,
                  const unsigned short* __restrict__ B,
                  const float* __restrict__ bias,
                  float* __restrict__ C,
                  int N, int K, int nbn, int bid, int nwg)
{
  const int tid = threadIdx.x;
  const int ln = tid & 63, wv = tid >> 6;
  const int wm = wv >> 2, wn = wv & 3;
  const int llo = ln & 15, lhi = ln >> 4;

  const int cpx = nwg >> 3;
  const int swz = (bid & 7) * cpx + (bid >> 3);
  const int bm = swz / nbn, bn = swz % nbn;
  const int m0 = bm * 256, n0 = bn * 256;

  const int srow = tid >> 3;
  const int sslot = (tid & 7) ^ (srow & 7);
  const unsigned short* Abase = A + (size_t)(m0 + srow) * K + sslot * 8;
  const unsigned short* Bbase = B + (size_t)(n0 + srow) * K + sslot * 8;
  const size_t rowK64 = (size_t)64 * K;
  char* ldsWaveDst = lds8 + (wv << 10);

  const int swz0 = ((lhi ^ (ln & 7)) << 4);
  const char* aRd0 = lds8 + (wm*64 + llo)*128 + swz0;
  const char* aRd1 = lds8 + (wm*64 + llo)*128 + (swz0 ^ 64);
  const char* bRd0 = lds8 + 65536 + (wn*32 + llo)*128 + swz0;
  const char* bRd1 = lds8 + 65536 + (wn*32 + llo)*128 + (swz0 ^ 64);

  auto ldA = [&](int b, int mf, int ks) -> short8 {
    const char* p = (ks ? aRd1 : aRd0) + b*32768 + (mf>>2)*16384 + (mf&3)*2048;
    return *reinterpret_cast<const short8*>(p);
  };
  auto ldB = [&](int b, int nf, int ks) -> short8 {
    const char* p = (ks ? bRd1 : bRd0) + b*32768 + (nf>>1)*16384 + (nf&1)*2048;
    return *reinterpret_cast<const short8*>(p);
  };

  f32x4 acc[8][4];
  #pragma unroll
  for (int m = 0; m < 8; ++m)
    #pragma unroll
    for (int n = 0; n < 4; ++n) acc[m][n] = 0.0f;

  STAGE(0, 0, 0, 0);
  STAGE(1, 0, 1, 0);
  STAGE(0, 0, 1, 0);
  STAGE(1, 0, 0, 0);
  STAGE(0, 1, 0, 1);
  STAGE(1, 1, 1, 1);
  asm volatile("s_waitcnt vmcnt(4)" ::: "memory");
  asm volatile("s_barrier" ::: "memory");

  short8 av[4][2], b0v[2][2], b1v[2][2];
  #pragma unroll 1
  for (int t0 = 0; t0 < T; t0 += 2){
    TILE(t0,   0);
    TILE(t0+1, 1);
  }

  asm volatile("s_nop 7\n\ts_nop 7\n\ts_nop 7" ::: );

  #pragma unroll
  for (int mf = 0; mf < 8; ++mf){
    const int row = m0 + (mf>>2)*128 + wm*64 + (mf&3)*16 + lhi*4;
    #pragma unroll
    for (int j = 0; j < 4; ++j){
      #pragma unroll
      for (int nf = 0; nf < 4; ++nf){
        const int col = n0 + (nf>>1)*128 + wn*32 + (nf&1)*16 + llo;
        C[(size_t)(row + j) * N + col] = acc[mf][nf][j] + bias[col];
      }
    }
  }
}

// ---------- fc1 body: m97-structure, 256 active threads of 512 ----------
__device__ __forceinline__
void fc1_body(char* lds, const unsigned short* __restrict__ A,
              const unsigned short* __restrict__ B,
              const float* __restrict__ bias, unsigned short* __restrict__ Cb, int fb)
{
  const int tid = threadIdx.x;
  if (tid >= 256){
    #pragma unroll 1
    for (int i = 0; i < 24; ++i){ __syncthreads(); __syncthreads(); }
    return;
  }
  unsigned short (*sA)[32] = (unsigned short(*)[32])lds;
  unsigned short (*sB)[32] = (unsigned short(*)[32])(lds + 8192);
  const int wv = tid >> 6, ln = tid & 63;
  const int wr = wv >> 1, wc = wv & 1;
  const int lhi = ln >> 4, llo = ln & 15;
  const int m0 = fb * 128;
  const int N = 128, K = 768;

  f32x4 acc[4][4];
  #pragma unroll
  for (int m = 0; m < 4; ++m)
    #pragma unroll
    for (int n = 0; n < 4; ++n) acc[m][n] = 0.0f;

  const int lrow = ln >> 2;
  const int lk8  = (ln & 3) * 8;

  #pragma unroll 1
  for (int kt = 0; kt < 768; kt += 32){
    #pragma unroll
    for (int cc = 0; cc < 2; ++cc){
      int c = wv * 2 + cc;
      gload16(A + (size_t)(m0 + c*16 + lrow) * K + kt + lk8, &sA[c*16][0]);
      gload16(B + (size_t)(c*16 + lrow) * K + kt + lk8, &sB[c*16][0]);
    }
    __syncthreads();

    short8 av[4], bv[4];
    #pragma unroll
    for (int m = 0; m < 4; ++m)
      av[m] = *reinterpret_cast<const short8*>(&sA[wr*64 + m*16 + llo][lhi*8]);
    #pragma unroll
    for (int n = 0; n < 4; ++n)
      bv[n] = *reinterpret_cast<const short8*>(&sB[wc*64 + n*16 + llo][lhi*8]);

    #pragma unroll
    for (int m = 0; m < 4; ++m)
      #pragma unroll
      for (int n = 0; n < 4; ++n)
        mfma16(acc[m][n], bv[n], av[m]);    // SWAPPED: acc = C[m-row][n-cols]
    __syncthreads();
  }

  asm volatile("s_nop 7\n\ts_nop 7\n\ts_nop 7" ::: );

  float4 bias4[4];
  #pragma unroll
  for (int n = 0; n < 4; ++n)
    bias4[n] = *reinterpret_cast<const float4*>(&bias[wc*64 + n*16 + lhi*4]);

  #pragma unroll
  for (int m = 0; m < 4; ++m){
    const int row = m0 + wr*64 + m*16 + llo;
    #pragma unroll
    for (int n = 0; n < 4; ++n){
      const int colbase = wc*64 + n*16 + lhi*4;
      ushort4 o;
      o.x = f2bf(acc[m][n][0] + bias4[n].x);
      o.y = f2bf(acc[m][n][1] + bias4[n].y);
      o.z = f2bf(acc[m][n][2] + bias4[n].z);
      o.w = f2bf(acc[m][n][3] + bias4[n].w);
      *reinterpret_cast<ushort4*>(&Cb[(size_t)row * N + colbase]) = o;
    }
  }
}

// ---------- mean body: 512 threads, contiguous bf16 reads ----------
__device__ __forceinline__
void mean_body(char* lds, const unsigned short* __restrict__ x1b,
               float* __restrict__ meanb, float* __restrict__ n1p, int mbid)
{
  float (*tmp)[128] = (float(*)[128])lds;   // [32][128] = 16 KB
  const int b = mbid / 6, cg = mbid % 6;
  const int tid = threadIdx.x;
  const int oct = tid & 15, rg = tid >> 4;
  const unsigned short* ip = x1b + (size_t)b*NT*CH + (size_t)rg*32*CH + cg*128 + oct*8;

  float s[8];
  #pragma unroll
  for (int j = 0; j < 8; ++j) s[j] = 0.f;
  #pragma unroll 4
  for (int r = 0; r < 32; ++r){
    short8 v = *reinterpret_cast<const short8*>(ip + (size_t)r*CH);
    #pragma unroll
    for (int j = 0; j < 8; ++j) s[j] += bf2f((unsigned short)v[j]);
  }
  #pragma unroll
  for (int j = 0; j < 8; ++j) tmp[rg][oct*8 + j] = s[j];
  __syncthreads();

  if (tid < 128){
    float m = 0.f;
    #pragma unroll
    for (int g = 0; g < 32; ++g) m += tmp[g][tid];
    m *= (1.0f/1024.0f);
    meanb[b*CH + cg*128 + tid] = m;
    float q = m * m;
    for (int off = 32; off; off >>= 1) q += __shfl_down(q, off, 64);
    if ((tid & 63) == 0) n1p[b*12 + cg*2 + (tid >> 6)] = q;
  }
}

// ---------- threefry2x32 (JAX), 20 rounds ----------
__device__ __forceinline__ void threefry(unsigned k0, unsigned k1, unsigned x0, unsigned x1,
                                         unsigned& o0, unsigned& o1){
  unsigned ks2 = k0 ^ k1 ^ 0x1BD11BDAu;
  x0 += k0; x1 += k1;
#define TFR(r) { x0 += x1; x1 = (x1 << r) | (x1 >> (32 - r)); x1 ^= x0; }
  TFR(13) TFR(15) TFR(26) TFR(6)  x0 += k1;  x1 += ks2 + 1u;
  TFR(17) TFR(29) TFR(16) TFR(24) x0 += ks2; x1 += k0 + 2u;
  TFR(13) TFR(15) TFR(26) TFR(6)  x0 += k0;  x1 += k1 + 3u;
  TFR(17) TFR(29) TFR(16) TFR(24) x0 += k1;  x1 += ks2 + 4u;
  TFR(13) TFR(15) TFR(26) TFR(6)  x0 += ks2; x1 += k0 + 5u;
#undef TFR
  o0 = x0; o1 = x1;
}

__device__ __forceinline__ float gumbel_from_bits(unsigned bits){
  float f = __uint_as_float((bits >> 9) | 0x3F800000u) - 1.0f;
  const float TINY = 1.17549435e-38f;
  float u = fmaxf(TINY, f + TINY);
  return -logf(-logf(u));
}

// ---------- router body: 512 threads, 2 tokens each; 1 barrier ----------
__device__ __forceinline__
void router_body(char* lds, const float* __restrict__ part, const float* __restrict__ n1p,
                 const float* __restrict__ r1w, const float* __restrict__ r1b,
                 const float* __restrict__ r2w, const float* __restrict__ r2b,
                 float* __restrict__ out, int b)
{
  float* cs   = (float*)lds;                 // [1024]
  float* red  = (float*)(lds + 4096);        // [16]
  float* w1s  = (float*)(lds + 4096 + 64);   // [128] x4
  float* b1s  = w1s + HIDN;
  float* w20s = b1s + HIDN;
  float* w21s = w20s + HIDN;
  const int tid = threadIdx.x;
  if (tid < HIDN){
    w1s[tid]  = r1w[tid];
    b1s[tid]  = r1b[tid];
    w20s[tid] = r2w[tid];
    w21s[tid] = r2w[HIDN + tid];
  }
  float n1s = 0.f;
  #pragma unroll
  for (int s = 0; s < 12; ++s) n1s += n1p[b*12 + s];
  float n1 = sqrtf(n1s);
  float lmin = 3.4e38f, lmax = -3.4e38f;
  #pragma unroll
  for (int j = 0; j < 2; ++j){
    int tk = tid + j*512;
    int t = b*NT + tk;
    float dot = 0.f, q = 0.f;
    #pragma unroll
    for (int s = 0; s < 12; ++s){
      dot += part[(size_t)s * MTOT + t];
      q   += part[(size_t)(12 + s) * MTOT + t];
    }
    float v = dot / (n1 * sqrtf(q));
    cs[tk] = v;
    lmin = fminf(lmin, v); lmax = fmaxf(lmax, v);
  }
  int ln = tid & 63, wv = tid >> 6;
  for (int off = 32; off; off >>= 1){
    lmin = fminf(lmin, __shfl_down(lmin, off, 64));
    lmax = fmaxf(lmax, __shfl_down(lmax, off, 64));
  }
  if (ln == 0){ red[wv] = lmin; red[8+wv] = lmax; }
  __syncthreads();
  float mn = red[0], mx = red[8];
  #pragma unroll
  for (int s = 1; s < 8; ++s){ mn = fminf(mn, red[s]); mx = fmaxf(mx, red[8+s]); }
  float rng = mx - mn;
  bool nz = (rng != 0.0f);

  const float r2b0 = r2b[0], r2b1 = r2b[1];
  float v[2], l0[2], l1[2];
  #pragma unroll
  for (int j = 0; j < 2; ++j){
    float c0 = cs[tid + j*512];
    v[j] = nz ? (c0 - mn) / rng : c0;
    l0[j] = r2b0; l1[j] = r2b1;
  }
  for (int k = 0; k < HIDN; ++k){
    float a = w1s[k], bb = b1s[k], c0 = w20s[k], c1 = w21s[k];
    #pragma unroll
    for (int j = 0; j < 2; ++j){
      float hh = fmaxf(v[j] * a + bb, 0.f);
      l0[j] += hh * c0;
      l1[j] += hh * c1;
    }
  }
  #pragma unroll
  for (int j = 0; j < 2; ++j){
    float s0 = 1.f / (1.f + expf(-l0[j]));
    float s1 = 1.f / (1.f + expf(-l1[j]));
    int t = b*NT + tid + j*512;
    unsigned o0, o1;
    threefry(0u, 42u, 0u, (unsigned)(2*t),     o0, o1);
    float g0 = gumbel_from_bits(o0 ^ o1);
    threefry(0u, 42u, 0u, (unsigned)(2*t + 1), o0, o1);
    float g1 = gumbel_from_bits(o0 ^ o1);
    out[t] = 1.f / (1.f + expf((s1 + g1) - (s0 + g0)));
  }
}

// ---------- combo 1: fc1 (128) | mean (96) — runs BEFORE the big GEMMs ----------
__global__ __launch_bounds__(512, 2)
void k_combo1(const unsigned short* __restrict__ xrb, const unsigned short* __restrict__ w1b,
              const float* __restrict__ fc1_b, unsigned short* __restrict__ t1dst,
              const unsigned short* __restrict__ x1b,
              float* __restrict__ meanb, float* __restrict__ n1p)
{
  __shared__ __align__(1024) char lds8[131072];
  const int bid = blockIdx.x;
  if (bid < 128){
    fc1_body(lds8, xrb, w1b, fc1_b, t1dst, bid);
  } else {
    mean_body(lds8, x1b, meanb, n1p, bid - 128);
  }
}

// ---------- combo 2: combined qkv GEMM (1152) | router (16) ----------
// A = [x1b; xrb] contiguous (M = 32768); C = [q1; q2] contiguous in d_out.
__global__ __launch_bounds__(512, 2)
void k_combo2(const unsigned short* __restrict__ Aall, const unsigned short* __restrict__ wqb,
              const float* __restrict__ qkv_b, float* __restrict__ q1q2,
              const float* __restrict__ part, const float* __restrict__ n1p,
              const float* __restrict__ r1w, const float* __restrict__ r1b,
              const float* __restrict__ r2w, const float* __restrict__ r2b,
              float* __restrict__ router)
{
  __shared__ __align__(1024) char lds8[131072];
  const int bid = blockIdx.x;
  if (bid < 1152){
    gemm256_body<CH/64>(lds8, Aall, wqb, qkv_b, q1q2, OUTF, CH, OUTF/256, bid, 1152);
  } else {
    router_body(lds8, part, n1p, r1w, r1b, r2w, r2b, router, bid - 1152);
  }
}

// ---------- m97-structure MFMA GEMM, fc2 (EPI1): refine + csim partials ----------
__global__ __launch_bounds__(256, 2)
void k_gemm_fc2(const unsigned short* __restrict__ A, const unsigned short* __restrict__ B,
                const float* __restrict__ bias, const unsigned short* __restrict__ addb,
                unsigned short* __restrict__ Cb,
                const float* __restrict__ meanb, float* __restrict__ part,
                int M, int N, int K)
{
  __shared__ unsigned short sA[128][32];
  __shared__ unsigned short sB[128][32];
  const int tid = threadIdx.x;
  const int wv = tid >> 6, ln = tid & 63;
  const int wr = wv >> 1, wc = wv & 1;
  const int lhi = ln >> 4, llo = ln & 15;
  const int m0 = blockIdx.x * 128, n0 = blockIdx.y * 128;

  f32x4 acc[4][4];
  #pragma unroll
  for (int m = 0; m < 4; ++m)
    #pragma unroll
    for (int n = 0; n < 4; ++n) acc[m][n] = 0.0f;

  const int lrow = ln >> 2;
  const int lk8  = (ln & 3) * 8;

  for (int kt = 0; kt < K; kt += 32){
    #pragma unroll
    for (int cc = 0; cc < 2; ++cc){
      int c = wv * 2 + cc;
      gload16(A + (size_t)(m0 + c*16 + lrow) * K + kt + lk8, &sA[c*16][0]);
      gload16(B + (size_t)(n0 + c*16 + lrow) * K + kt + lk8, &sB[c*16][0]);
    }
    __syncthreads();

    short8 av[4], bv[4];
    #pragma unroll
    for (int m = 0; m < 4; ++m)
      av[m] = *reinterpret_cast<const short8*>(&sA[wr*64 + m*16 + llo][lhi*8]);
    #pragma unroll
    for (int n = 0; n < 4; ++n)
      bv[n] = *reinterpret_cast<const short8*>(&sB[wc*64 + n*16 + llo][lhi*8]);

    #pragma unroll
    for (int m = 0; m < 4; ++m)
      #pragma unroll
      for (int n = 0; n < 4; ++n)
        mfma16(acc[m][n], bv[n], av[m]);    // SWAPPED
    __syncthreads();
  }

  asm volatile("s_nop 7\n\ts_nop 7\n\ts_nop 7" ::: );

  float4 bias4[4];
  #pragma unroll
  for (int n = 0; n < 4; ++n)
    bias4[n] = *reinterpret_cast<const float4*>(&bias[n0 + wc*64 + n*16 + lhi*4]);

  const int bb = m0 >> 10;
  const float* mp = meanb + bb * CH;
  float4 mp4[4];
  #pragma unroll
  for (int n = 0; n < 4; ++n)
    mp4[n] = *reinterpret_cast<const float4*>(&mp[n0 + wc*64 + n*16 + lhi*4]);

  #pragma unroll
  for (int m = 0; m < 4; ++m){
    const int row = m0 + wr*64 + m*16 + llo;
    float dsum = 0.f, qsum = 0.f;
    #pragma unroll
    for (int n = 0; n < 4; ++n){
      const int colbase = n0 + wc*64 + n*16 + lhi*4;
      ushort4 a4 = *reinterpret_cast<const ushort4*>(&addb[(size_t)row * N + colbase]);
      float v0 = acc[m][n][0] + bias4[n].x + bf2f(a4.x);
      float v1 = acc[m][n][1] + bias4[n].y + bf2f(a4.y);
      float v2 = acc[m][n][2] + bias4[n].z + bf2f(a4.z);
      float v3 = acc[m][n][3] + bias4[n].w + bf2f(a4.w);
      ushort4 o; o.x = f2bf(v0); o.y = f2bf(v1); o.z = f2bf(v2); o.w = f2bf(v3);
      *reinterpret_cast<ushort4*>(&Cb[(size_t)row * N + colbase]) = o;
      dsum += v0*mp4[n].x + v1*mp4[n].y + v2*mp4[n].z + v3*mp4[n].w;
      qsum += v0*v0 + v1*v1 + v2*v2 + v3*v3;
    }
    dsum += __shfl_xor(dsum, 16, 64);  qsum += __shfl_xor(qsum, 16, 64);
    dsum += __shfl_xor(dsum, 32, 64);  qsum += __shfl_xor(qsum, 32, 64);
    if (ln < 16){
      const int slot = blockIdx.y * 2 + wc;            // 0..11
      part[(size_t)slot * MTOT + row] = dsum;
      part[(size_t)(12 + slot) * MTOT + row] = qsum;
    }
  }
}

// ---------- depthwise 3x3 SAME conv over 32x32 + bias + exact GELU (bf16) ----------
__global__ void k_dwgelu(const unsigned short* __restrict__ t1b, const float* __restrict__ dww,
                         const float* __restrict__ dwb, unsigned short* __restrict__ t2)
{
  int idx = blockIdx.x * blockDim.x + threadIdx.x;
  int hq = idx & 31; int t = idx >> 5;
  int h = hq * 4;
  int n = t & (NT-1); int b = t >> 10;
  int y = n >> 5, x = n & 31;

  float w[4][9];
  #pragma unroll
  for (int i = 0; i < 4; ++i)
    #pragma unroll
    for (int k = 0; k < 9; ++k) w[i][k] = dww[(h+i)*9 + k];

  float a0 = dwb[h+0], a1 = dwb[h+1], a2 = dwb[h+2], a3 = dwb[h+3];
  #pragma unroll
  for (int dy = -1; dy <= 1; ++dy){
    int yy = y + dy; if ((unsigned)yy >= 32u) continue;
    #pragma unroll
    for (int dx = -1; dx <= 1; ++dx){
      int xx = x + dx; if ((unsigned)xx >= 32u) continue;
      ushort4 v = *reinterpret_cast<const ushort4*>(&t1b[((size_t)b*NT + yy*32 + xx)*HIDN + h]);
      int k = (dy+1)*3 + (dx+1);
      a0 += bf2f(v.x) * w[0][k]; a1 += bf2f(v.y) * w[1][k];
      a2 += bf2f(v.z) * w[2][k]; a3 += bf2f(v.w) * w[3][k];
    }
  }
  const float is2 = 0.70710678118654752440f;
  a0 = 0.5f*a0*(1.0f + erff(a0*is2));
  a1 = 0.5f*a1*(1.0f + erff(a1*is2));
  a2 = 0.5f*a2*(1.0f + erff(a2*is2));
  a3 = 0.5f*a3*(1.0f + erff(a3*is2));
  ushort4 o; o.x = f2bf(a0); o.y = f2bf(a1); o.z = f2bf(a2); o.w = f2bf(a3);
  *reinterpret_cast<ushort4*>(&t2[(size_t)t*HIDN + h]) = o;
}

extern "C" void kernel_launch(void* const* d_in, const int* in_sizes, int n_in,
                              void* d_out, int out_size, void* d_ws, size_t ws_size,
                              hipStream_t stream)
{
  (void)in_sizes; (void)n_in; (void)out_size;
  const float* input  = (const float*)d_in[0];
  const float* input2 = (const float*)d_in[3];
  const float* qkv_w  = (const float*)d_in[4];
  const float* qkv_b  = (const float*)d_in[5];
  const float* fc1_w  = (const float*)d_in[6];
  const float* fc1_b  = (const float*)d_in[7];
  const float* dw_w   = (const float*)d_in[8];
  const float* dw_b   = (const float*)d_in[9];
  const float* fc2_w  = (const float*)d_in[10];
  const float* fc2_b  = (const float*)d_in[11];
  const float* r1_w   = (const float*)d_in[12];
  const float* r1_b   = (const float*)d_in[13];
  const float* r2_w   = (const float*)d_in[14];
  const float* r2_b   = (const float*)d_in[15];

  float* q1 = (float*)d_out;
  float* router = q1 + (size_t)2 * MTOT * OUTF;

  if (ws_size < 67000000u) return;

  char* ws = (char*)d_ws;
  unsigned short* x1b = (unsigned short*)ws; ws += (size_t)MTOT*CH*2;   // input bf16   } contiguous:
  unsigned short* xrb = (unsigned short*)ws; ws += (size_t)MTOT*CH*2;   // refine bf16  } A=[x1b;xrb]
  unsigned short* wqb = (unsigned short*)ws; ws += (size_t)OUTF*CH*2;
  unsigned short* w1b = (unsigned short*)ws; ws += (size_t)HIDN*CH*2;
  unsigned short* w2b = (unsigned short*)ws; ws += (size_t)CH*HIDN*2;
  unsigned short* t1b = (unsigned short*)ws; ws += (size_t)MTOT*HIDN*4; // 8MB region: part | t1dst
  unsigned short* t2  = (unsigned short*)ws; ws += (size_t)MTOT*HIDN*2;
  float*          mb  = (float*)ws;          ws += (size_t)BQ*CH*4;
  float*          n1p = (float*)ws;          ws += 1024;               // [16][12] partials
  float*          part= (float*)t1b;         // csim partials [24][16384] alias region

  // 1) fused grid-stride convert for all 5 tensors
  k_f2bf_all<<<dim3(2048), 256, 0, stream>>>(
      input, input2, qkv_w, fc1_w, fc2_w, x1b, xrb, wqb, w1b, w2b);

  // 2) combo1: fc1 (128 blocks) | mean (96)  — fast, frees the fc-chain early
  unsigned short* t1dst = t1b + (size_t)MTOT*HIDN;  // upper half of region
  k_combo1<<<dim3(224), 512, 0, stream>>>(
      xrb, w1b, fc1_b, t1dst, x1b, mb, n1p);

  // 3) depthwise conv + gelu -> t2 bf16
  k_dwgelu<<<dim3(MTOT*32/256), 256, 0, stream>>>(t1dst, dw_w, dw_b, t2);

  // 4) fc2 + input2(bf16) add -> refine bf16 (into xrb) + csim partials -> part
  k_gemm_fc2<<<dim3(MTOT/128, CH/128), 256, 0, stream>>>(
      t2, w2b, fc2_b, xrb, xrb, mb, part, MTOT, CH, HIDN);

  // 5) combo2: combined qkv [q1;q2] GEMM (1152 blocks) | router (16)
  k_combo2<<<dim3(1168), 512, 0, stream>>>(
      x1b, wqb, qkv_b, q1, part, n1p, r1_w, r1_b, r2_w, r2_b, router);
}